// Round 4
// baseline (84.736 us; speedup 1.0000x reference)
//
#include <hip/hip_runtime.h>
#include <hip/hip_fp16.h>

#define NB 32
#define NTT 4096
#define ND 256
#define NK 64
#define CHUNK 128
#define THREADS 512

typedef __attribute__((ext_vector_type(8))) short short8;
typedef __attribute__((ext_vector_type(4))) float f32x4;

__device__ __forceinline__ unsigned short f2h(float f) {
    return __half_as_ushort(__float2half(f));
}
__device__ __forceinline__ unsigned int pkrtz(float a, float b) {
    union { __fp16 __attribute__((ext_vector_type(2))) v; unsigned int u; } x;
    x.v = __builtin_amdgcn_cvt_pkrtz(a, b);
    return x.u;
}
__device__ __forceinline__ short8 mk8(unsigned int a, unsigned int b,
                                      unsigned int c, unsigned int d) {
    union { unsigned int u[4]; short8 s; } x;
    x.u[0] = a; x.u[1] = b; x.u[2] = c; x.u[3] = d; return x.s;
}

// ---- LDS layout (bytes) ----
// WT : [64 k][256 d] fp16 swizzled : byte = k*512 + ((2d) ^ ((k&7)<<4))   (32 KB)
// AT : 2 x [64 k][128 t] fp16 swizzled : k*256 + ((2t) ^ ((k&7)<<4))      (2 x 16 KB)
#define WT_OFF 0
#define AT_OFF 32768
#define SM_BYTES 65536

__device__ __forceinline__ int wt_byte(int k, int d) { return WT_OFF + k * 512 + ((2 * d) ^ ((k & 7) << 4)); }
__device__ __forceinline__ int at_byte(int buf, int k, int t) { return AT_OFF + buf * 16384 + k * 256 + ((2 * t) ^ ((k & 7) << 4)); }

// Fused: logits = x@W + b ; A = softmax_k ; Spart += A^T @ x ; spart = colsum(A)
// GEMM1 computes L^T = mfma(A=W_frag, B=Xrow_frag): lane holds 16 logits of
// ONE row t=16w+lo (k = 16mt+4hi+r) -> softmax = in-reg tree + 2 shfl_xor.
// GEMM2 unchanged; colsum via ones-MFMA on A^T frags (wave 0).
__global__ __launch_bounds__(THREADS, 4) void nv_k1(const float* __restrict__ x,
                                                    const float* __restrict__ aw,
                                                    const float* __restrict__ ab,
                                                    float* __restrict__ Sp,
                                                    float* __restrict__ sp,
                                                    int P) {
    __shared__ char SM[SM_BYTES];
    const int tid  = threadIdx.x;
    const int w    = tid >> 6;        // wave 0..7
    const int lane = tid & 63;
    const int lo   = lane & 15;
    const int hi   = lane >> 4;
    const int wg   = blockIdx.x;
    const int b    = wg / P;
    const int p    = wg % P;
    const int rowsPer = NTT / P;
    const int nch  = rowsPer / CHUNK;

    // ---- stage W^T vectorized: wave w handles d-group w*4 + 32*it, k = lane ----
    // aw is [d][k] row-major; lanes read 64 consecutive floats (coalesced).
#pragma unroll
    for (int it = 0; it < 8; ++it) {
        int d0 = it * 32 + w * 4;
        float f0 = aw[(size_t)(d0 + 0) * 64 + lane];
        float f1 = aw[(size_t)(d0 + 1) * 64 + lane];
        float f2 = aw[(size_t)(d0 + 2) * 64 + lane];
        float f3 = aw[(size_t)(d0 + 3) * 64 + lane];
        unsigned long long v = (unsigned long long)pkrtz(f0, f1)
                             | ((unsigned long long)pkrtz(f2, f3) << 32);
        *(unsigned long long*)(SM + wt_byte(lane, d0)) = v;
    }
    __syncthreads();

    // S accumulator: wave w owns d-strip [32w, 32w+32), all 64 k rows
    f32x4 Sacc[4][2];
#pragma unroll
    for (int mt = 0; mt < 4; ++mt)
#pragma unroll
        for (int nt = 0; nt < 2; ++nt) Sacc[mt][nt] = (f32x4){0.f, 0.f, 0.f, 0.f};
    f32x4 acc_cs[4];
#pragma unroll
    for (int mt = 0; mt < 4; ++mt) acc_cs[mt] = (f32x4){0.f, 0.f, 0.f, 0.f};

    short8 ones;
#pragma unroll
    for (int j = 0; j < 8; ++j) ones[j] = (short)0x3C00;

    const float* xb = x + (size_t)b * NTT * ND;

    for (int c = 0; c < nch; ++c) {
        const int t0 = p * rowsPer + c * CHUNK;
        const int buf = c & 1;

        // ---- row-fragment loads + cvt: lane owns row t0 + 16w + lo, d-quarter hi ----
        const float* rowp = xb + (size_t)(t0 + 16 * w + lo) * ND;
        short8 rf16[8];
#pragma unroll
        for (int ds = 0; ds < 8; ++ds) {
            f32x4 a  = *(const f32x4*)(rowp + 32 * ds + 8 * hi);
            f32x4 b2 = *(const f32x4*)(rowp + 32 * ds + 8 * hi + 4);
            rf16[ds] = mk8(pkrtz(a[0], a[1]), pkrtz(a[2], a[3]),
                           pkrtz(b2[0], b2[1]), pkrtz(b2[2], b2[3]));
        }

        // ---- GEMM1 (swapped): L^T[k][t], A-op = W frags, B-op = X row frags ----
        f32x4 acc1[4];
#pragma unroll
        for (int mt = 0; mt < 4; ++mt) acc1[mt] = (f32x4){0.f, 0.f, 0.f, 0.f};
#pragma unroll
        for (int ds = 0; ds < 8; ++ds) {
#pragma unroll
            for (int mt = 0; mt < 4; ++mt) {
                short8 wf = *(const short8*)(SM + wt_byte(16 * mt + lo, 32 * ds + 8 * hi));
                acc1[mt] = __builtin_amdgcn_mfma_f32_16x16x32_f16(wf, rf16[ds], acc1[mt], 0, 0, 0);
            }
        }

        // ---- issue GEMM2 column loads for ts=0 (hidden under softmax) ----
        float cvA[16], cvB[16];
#pragma unroll
        for (int nt = 0; nt < 2; ++nt)
#pragma unroll
            for (int j = 0; j < 8; ++j)
                cvA[nt * 8 + j] = xb[(size_t)(t0 + 8 * hi + j) * ND + 32 * w + 16 * nt + lo];

        // ---- softmax over k: lane holds logits for row t=16w+lo, k=16mt+4hi+r ----
        {
            float vals[4][4];
            float m = -3.0e38f;
#pragma unroll
            for (int mt = 0; mt < 4; ++mt) {
                f32x4 bias = *(const f32x4*)(ab + 16 * mt + 4 * hi);
#pragma unroll
                for (int r = 0; r < 4; ++r) {
                    float v = acc1[mt][r] + bias[r];
                    vals[mt][r] = v;
                    m = fmaxf(m, v);
                }
            }
            m = fmaxf(m, __shfl_xor(m, 16));
            m = fmaxf(m, __shfl_xor(m, 32));
            float s = 0.f;
#pragma unroll
            for (int mt = 0; mt < 4; ++mt)
#pragma unroll
                for (int r = 0; r < 4; ++r) {
                    float e = __expf(vals[mt][r] - m);
                    vals[mt][r] = e;
                    s += e;
                }
            s += __shfl_xor(s, 16);
            s += __shfl_xor(s, 32);
            float inv = 1.0f / s;
            // write A^T: AT[k = 16mt+4hi+r][t = 16w+lo], scalar u16
#pragma unroll
            for (int mt = 0; mt < 4; ++mt)
#pragma unroll
                for (int r = 0; r < 4; ++r) {
                    unsigned short h = f2h(vals[mt][r] * inv);
                    *(unsigned short*)(SM + at_byte(buf, 16 * mt + 4 * hi + r, 16 * w + lo)) = h;
                }
        }
        __syncthreads();   // single barrier per chunk (AT double-buffered)

        // ---- GEMM2: S[k][d] += A^T[k][t] X[t][d]; 4 ts-slices, col-load dbuf ----
#pragma unroll
        for (int ts = 0; ts < 4; ++ts) {
            short8 af[4];
#pragma unroll
            for (int mt = 0; mt < 4; ++mt)
                af[mt] = *(const short8*)(SM + at_byte(buf, 16 * mt + lo, 32 * ts + 8 * hi));
            // issue next ts-slice col loads before consuming this slice
            if (ts < 3) {
                float* nxt = (ts & 1) ? cvA : cvB;
#pragma unroll
                for (int nt = 0; nt < 2; ++nt)
#pragma unroll
                    for (int j = 0; j < 8; ++j)
                        nxt[nt * 8 + j] = xb[(size_t)(t0 + 32 * (ts + 1) + 8 * hi + j) * ND + 32 * w + 16 * nt + lo];
            }
            if (w == 0) {
#pragma unroll
                for (int mt = 0; mt < 4; ++mt)
                    acc_cs[mt] = __builtin_amdgcn_mfma_f32_16x16x32_f16(af[mt], ones, acc_cs[mt], 0, 0, 0);
            }
            const float* cur = (ts & 1) ? cvB : cvA;
#pragma unroll
            for (int nt = 0; nt < 2; ++nt) {
                short8 bf = mk8(pkrtz(cur[nt * 8 + 0], cur[nt * 8 + 1]),
                                pkrtz(cur[nt * 8 + 2], cur[nt * 8 + 3]),
                                pkrtz(cur[nt * 8 + 4], cur[nt * 8 + 5]),
                                pkrtz(cur[nt * 8 + 6], cur[nt * 8 + 7]));
#pragma unroll
                for (int mt = 0; mt < 4; ++mt)
                    Sacc[mt][nt] = __builtin_amdgcn_mfma_f32_16x16x32_f16(af[mt], bf, Sacc[mt][nt], 0, 0, 0);
            }
        }
    }

    // ---- colsum write (wave 0; D cols identical, take lo==0 lanes) ----
    if (w == 0 && lo == 0) {
#pragma unroll
        for (int mt = 0; mt < 4; ++mt)
#pragma unroll
            for (int r = 0; r < 4; ++r)
                sp[(size_t)wg * 64 + 16 * mt + 4 * hi + r] = acc_cs[mt][r];
    }

    // ---- write partial S: k = 16mt + 4hi + r, d = 32w + 16nt + lo ----
#pragma unroll
    for (int mt = 0; mt < 4; ++mt)
#pragma unroll
        for (int nt = 0; nt < 2; ++nt)
#pragma unroll
            for (int r = 0; r < 4; ++r) {
                int kc = 16 * mt + 4 * hi + r;
                int d  = 32 * w + 16 * nt + lo;
                Sp[((size_t)wg * 64 + kc) * 256 + d] = Sacc[mt][nt][r];
            }
}

// Reduce partials, subtract colsum*centroid, L2-normalize per (b,k) row.
__global__ __launch_bounds__(256) void nv_k2(const float* __restrict__ Sp,
                                             const float* __restrict__ sp,
                                             const float* __restrict__ cent,
                                             float* __restrict__ out,
                                             int P) {
    const int bk = blockIdx.x;
    const int b  = bk >> 6;
    const int k  = bk & 63;
    const int d  = threadIdx.x;

    float s = 0.f;
    for (int p = 0; p < P; ++p)
        s += Sp[(((size_t)(b * P + p)) * 64 + k) * 256 + d];
    float cv = 0.f;
    for (int p = 0; p < P; ++p)
        cv += sp[(size_t)(b * P + p) * 64 + k];

    float v = s - cv * cent[k * 256 + d];

    float ss = v * v;
    ss += __shfl_xor(ss, 1);
    ss += __shfl_xor(ss, 2);
    ss += __shfl_xor(ss, 4);
    ss += __shfl_xor(ss, 8);
    ss += __shfl_xor(ss, 16);
    ss += __shfl_xor(ss, 32);
    __shared__ float red[4];
    const int wv = threadIdx.x >> 6, ln = threadIdx.x & 63;
    if (ln == 0) red[wv] = ss;
    __syncthreads();
    float tot = red[0] + red[1] + red[2] + red[3];
    float rn = 1.0f / fmaxf(sqrtf(tot), 1e-12f);
    out[((size_t)b * 64 + k) * 256 + d] = v * rn;
}

extern "C" void kernel_launch(void* const* d_in, const int* in_sizes, int n_in,
                              void* d_out, int out_size, void* d_ws, size_t ws_size,
                              hipStream_t stream) {
    (void)in_sizes; (void)n_in; (void)out_size;
    const float* x  = (const float*)d_in[0];
    const float* ct = (const float*)d_in[1];
    const float* aw = (const float*)d_in[2];
    const float* ab = (const float*)d_in[3];
    float* out = (float*)d_out;

    const size_t PSZ = (size_t)NB * NK * ND * sizeof(float);  // 2 MB per partial set
    int P = 0;
    const int cands[5] = {16, 8, 4, 2, 1};   // rowsPer = 4096/P must be %128==0
    for (int i = 0; i < 5; ++i) {
        size_t need = (size_t)cands[i] * PSZ + (size_t)cands[i] * NB * NK * sizeof(float);
        if (need <= ws_size) { P = cands[i]; break; }
    }
    float* Sp;
    float* sp;
    if (P > 0) {
        Sp = (float*)d_ws;
        sp = (float*)((char*)d_ws + (size_t)P * PSZ);
    } else {
        P = 1;
        Sp = out;
        sp = (float*)d_ws;
    }

    nv_k1<<<dim3(NB * P), dim3(THREADS), 0, stream>>>(x, aw, ab, Sp, sp, P);
    nv_k2<<<dim3(NB * NK), dim3(256), 0, stream>>>(Sp, sp, ct, out, P);
}